// Round 2
// baseline (10.771 us; speedup 1.0000x reference)
//
#include <hip/hip_runtime.h>
#include <math.h>

// Problem dims: A=24, D=16.
// Output layout (concat flat, return order):
//   [0..23]    out          = tanh(dec stack)
//   [24..87]   in_diff_sum  = pairwise L2 over rows of x.reshape(8,3)
//   [88..151]  lat_diff_sum = all zeros (faithful bug reproduction)
//   [152..167] lat_repr     = y (latent, 16)

#define AE_A 24
#define AE_D 16
#define NT   256

// LDS layout (floats). Weight rows padded (stride 25 / 17) to break the
// stride-24 (8-way) / stride-16 (16-way) bank-conflict patterns.
constexpr int OF_EW0 = 0;                 // 24 x 25
constexpr int OF_EW1 = OF_EW0 + 600;      // 24 x 25
constexpr int OF_EW2 = OF_EW1 + 600;      // 24 x 25
constexpr int OF_EW3 = OF_EW2 + 600;      // 16 x 25
constexpr int OF_DW0 = OF_EW3 + 400;      // 24 x 17
constexpr int OF_DW1 = OF_DW0 + 408;      // 24 x 25
constexpr int OF_DW2 = OF_DW1 + 600;      // 24 x 25
constexpr int OF_DW3 = OF_DW2 + 600;      // 24 x 25
constexpr int OF_EB0 = OF_DW3 + 600;
constexpr int OF_EB1 = OF_EB0 + 24;
constexpr int OF_EB2 = OF_EB1 + 24;
constexpr int OF_EB3 = OF_EB2 + 24;       // 16
constexpr int OF_DB0 = OF_EB3 + 16;
constexpr int OF_DB1 = OF_DB0 + 24;
constexpr int OF_DB2 = OF_DB1 + 24;
constexpr int OF_DB3 = OF_DB2 + 24;
constexpr int OF_X   = OF_DB3 + 24;       // 24
constexpr int OF_HA  = OF_X + 24;         // 24
constexpr int OF_HB  = OF_HA + 24;        // 24
constexpr int OF_Y   = OF_HB + 24;        // 16
constexpr int LDS_TOT = OF_Y + 16;

template <int ROWS, int COLS, int STRIDE>
__device__ __forceinline__ void stage(float* __restrict__ dst,
                                      const float* __restrict__ src, int tid) {
    constexpr int N = ROWS * COLS;
    #pragma unroll
    for (int base = 0; base < N; base += NT) {
        const int i = base + tid;
        if (i < N) dst[(i / COLS) * STRIDE + (i % COLS)] = src[i];
    }
}

// 4-accumulator dot product: cuts the dependent-FMA chain from K to K/4.
template <int K>
__device__ __forceinline__ float dotk(const float* __restrict__ w,
                                      const float* __restrict__ h, float bias) {
    float a0 = bias, a1 = 0.f, a2 = 0.f, a3 = 0.f;
    #pragma unroll
    for (int k = 0; k < K; k += 4) {
        a0 = fmaf(w[k + 0], h[k + 0], a0);
        a1 = fmaf(w[k + 1], h[k + 1], a1);
        a2 = fmaf(w[k + 2], h[k + 2], a2);
        a3 = fmaf(w[k + 3], h[k + 3], a3);
    }
    return (a0 + a1) + (a2 + a3);
}

__global__ __launch_bounds__(NT) void ae_fwd_kernel(
    const float* __restrict__ x,
    const float* __restrict__ ew0, const float* __restrict__ eb0,
    const float* __restrict__ ew1, const float* __restrict__ eb1,
    const float* __restrict__ ew2, const float* __restrict__ eb2,
    const float* __restrict__ ew3, const float* __restrict__ eb3,
    const float* __restrict__ dw0, const float* __restrict__ db0,
    const float* __restrict__ dw1, const float* __restrict__ db1,
    const float* __restrict__ dw2, const float* __restrict__ db2,
    const float* __restrict__ dw3, const float* __restrict__ db3,
    float* __restrict__ out)
{
    __shared__ float L[LDS_TOT];
    const int t = threadIdx.x;

    // ---- stage EVERYTHING up-front: all global loads issued before any
    // dependency, so the full ~17 KB costs ~one HBM latency. ----
    stage<AE_A, AE_A, 25>(&L[OF_EW0], ew0, t);
    stage<AE_A, AE_A, 25>(&L[OF_EW1], ew1, t);
    stage<AE_A, AE_A, 25>(&L[OF_EW2], ew2, t);
    stage<AE_D, AE_A, 25>(&L[OF_EW3], ew3, t);
    stage<AE_A, AE_D, 17>(&L[OF_DW0], dw0, t);
    stage<AE_A, AE_A, 25>(&L[OF_DW1], dw1, t);
    stage<AE_A, AE_A, 25>(&L[OF_DW2], dw2, t);
    stage<AE_A, AE_A, 25>(&L[OF_DW3], dw3, t);
    if (t < AE_A) {
        L[OF_EB0 + t] = eb0[t];
        L[OF_EB1 + t] = eb1[t];
        L[OF_EB2 + t] = eb2[t];
        L[OF_DB0 + t] = db0[t];
        L[OF_DB1 + t] = db1[t];
        L[OF_DB2 + t] = db2[t];
        L[OF_DB3 + t] = db3[t];
        L[OF_X   + t] = x[t];
    }
    if (t < AE_D) L[OF_EB3 + t] = eb3[t];
    __syncthreads();

    // ---- wave 1: pairwise-distance outputs, concurrent with the layer chain
    if (t >= 64 && t < 128) {
        const int p = t - 64;
        const int m = p >> 3;
        const int n = p & 7;
        const float d0 = L[OF_X + m * 3 + 0] - L[OF_X + n * 3 + 0];
        const float d1 = L[OF_X + m * 3 + 1] - L[OF_X + n * 3 + 1];
        const float d2 = L[OF_X + m * 3 + 2] - L[OF_X + n * 3 + 2];
        out[24 + p] = sqrtf(d0 * d0 + d1 * d1 + d2 * d2);
        out[88 + p] = 0.0f;
    }

    // ---- wave 0: layer chain (all LDS-resident) ----
    if (t < AE_A)
        L[OF_HA + t] = fmaxf(dotk<AE_A>(&L[OF_EW0 + t * 25], &L[OF_X], L[OF_EB0 + t]), 0.f);
    __syncthreads();
    if (t < AE_A)
        L[OF_HB + t] = fmaxf(dotk<AE_A>(&L[OF_EW1 + t * 25], &L[OF_HA], L[OF_EB1 + t]), 0.f);
    __syncthreads();
    if (t < AE_A)
        L[OF_HA + t] = fmaxf(dotk<AE_A>(&L[OF_EW2 + t * 25], &L[OF_HB], L[OF_EB2 + t]), 0.f);
    __syncthreads();
    if (t < AE_D) {
        const float acc = dotk<AE_A>(&L[OF_EW3 + t * 25], &L[OF_HA], L[OF_EB3 + t]);
        L[OF_Y + t] = acc;
        out[152 + t] = acc;
    }
    __syncthreads();
    if (t < AE_A)
        L[OF_HA + t] = fmaxf(dotk<AE_D>(&L[OF_DW0 + t * 17], &L[OF_Y], L[OF_DB0 + t]), 0.f);
    __syncthreads();
    if (t < AE_A)
        L[OF_HB + t] = fmaxf(dotk<AE_A>(&L[OF_DW1 + t * 25], &L[OF_HA], L[OF_DB1 + t]), 0.f);
    __syncthreads();
    if (t < AE_A)
        L[OF_HA + t] = fmaxf(dotk<AE_A>(&L[OF_DW2 + t * 25], &L[OF_HB], L[OF_DB2 + t]), 0.f);
    __syncthreads();
    if (t < AE_A)
        out[t] = tanhf(dotk<AE_A>(&L[OF_DW3 + t * 25], &L[OF_HA], L[OF_DB3 + t]));
}

extern "C" void kernel_launch(void* const* d_in, const int* in_sizes, int n_in,
                              void* d_out, int out_size, void* d_ws, size_t ws_size,
                              hipStream_t stream) {
    (void)in_sizes; (void)n_in; (void)d_ws; (void)ws_size; (void)out_size;

    const float* x   = (const float*)d_in[0];
    const float* ew0 = (const float*)d_in[1];
    const float* eb0 = (const float*)d_in[2];
    const float* ew1 = (const float*)d_in[3];
    const float* eb1 = (const float*)d_in[4];
    const float* ew2 = (const float*)d_in[5];
    const float* eb2 = (const float*)d_in[6];
    const float* ew3 = (const float*)d_in[7];
    const float* eb3 = (const float*)d_in[8];
    const float* dw0 = (const float*)d_in[9];
    const float* db0 = (const float*)d_in[10];
    const float* dw1 = (const float*)d_in[11];
    const float* db1 = (const float*)d_in[12];
    const float* dw2 = (const float*)d_in[13];
    const float* db2 = (const float*)d_in[14];
    const float* dw3 = (const float*)d_in[15];
    const float* db3 = (const float*)d_in[16];
    float* out = (float*)d_out;

    ae_fwd_kernel<<<1, NT, 0, stream>>>(
        x, ew0, eb0, ew1, eb1, ew2, eb2, ew3, eb3,
        dw0, db0, dw1, db1, dw2, db2, dw3, db3, out);
}

// Round 3
// 9.680 us; speedup vs baseline: 1.1127x; 1.1127x over previous
//
#include <hip/hip_runtime.h>
#include <math.h>

// Problem dims: A=24, D=16.
// Output layout (concat flat, return order):
//   [0..23]    out          = tanh(dec stack)
//   [24..87]   in_diff_sum  = pairwise L2 over rows of x.reshape(8,3)
//   [88..151]  lat_diff_sum = all zeros (faithful bug reproduction)
//   [152..167] lat_repr     = y (latent, 16)
//
// Single wave64, zero LDS, zero barriers. Activation h[k] lives in lane k;
// broadcast via __shfl. Weight rows software-pipelined through two register
// buffers so each layer's L2 load latency hides under the previous layer's
// shuffle-FMA chain.

#define AE_A 24
#define AE_D 16

__device__ __forceinline__ void ld24(float* __restrict__ w, const float* __restrict__ p) {
    // rows are 96B-stride, 16B-aligned -> 6x global_load_dwordx4
    const float4* q = (const float4*)p;
    #pragma unroll
    for (int i = 0; i < 6; ++i) {
        float4 v = q[i];
        w[4 * i + 0] = v.x; w[4 * i + 1] = v.y; w[4 * i + 2] = v.z; w[4 * i + 3] = v.w;
    }
}

__device__ __forceinline__ void ld16(float* __restrict__ w, const float* __restrict__ p) {
    const float4* q = (const float4*)p;
    #pragma unroll
    for (int i = 0; i < 4; ++i) {
        float4 v = q[i];
        w[4 * i + 0] = v.x; w[4 * i + 1] = v.y; w[4 * i + 2] = v.z; w[4 * i + 3] = v.w;
    }
}

// dot over K lanes' h via shuffle broadcast, 4 accumulators (chain K/4 deep).
template <int K>
__device__ __forceinline__ float dot_shfl(const float* __restrict__ w, float h, float bias) {
    float a0 = bias, a1 = 0.f, a2 = 0.f, a3 = 0.f;
    #pragma unroll
    for (int k = 0; k < K; k += 4) {
        a0 = fmaf(w[k + 0], __shfl(h, k + 0), a0);
        a1 = fmaf(w[k + 1], __shfl(h, k + 1), a1);
        a2 = fmaf(w[k + 2], __shfl(h, k + 2), a2);
        a3 = fmaf(w[k + 3], __shfl(h, k + 3), a3);
    }
    return (a0 + a1) + (a2 + a3);
}

__global__ __launch_bounds__(64) void ae_fwd_kernel(
    const float* __restrict__ x,
    const float* __restrict__ ew0, const float* __restrict__ eb0,
    const float* __restrict__ ew1, const float* __restrict__ eb1,
    const float* __restrict__ ew2, const float* __restrict__ eb2,
    const float* __restrict__ ew3, const float* __restrict__ eb3,
    const float* __restrict__ dw0, const float* __restrict__ db0,
    const float* __restrict__ dw1, const float* __restrict__ db1,
    const float* __restrict__ dw2, const float* __restrict__ db2,
    const float* __restrict__ dw3, const float* __restrict__ db3,
    float* __restrict__ out)
{
    const int t   = threadIdx.x;
    const int r24 = t < AE_A ? t : AE_A - 1;   // clamped row: loads stay converged
    const int r16 = t < AE_D ? t : AE_D - 1;

    float wa[AE_A], wb[AE_A];

    // ---- issue everything independent up-front ----
    ld24(wa, ew0 + r24 * AE_A);                 // L0 weights in flight
    const float xv = x[r24];                    // lane t holds x[t] (t<24 valid)
    const float b0 = eb0[r24], b1 = eb1[r24], b2 = eb2[r24];
    const float b3 = eb3[r16];
    const float b4 = db0[r24], b5 = db1[r24], b6 = db2[r24], b7 = db3[r24];

    // ---- pairwise distances (only needs xv) — overlaps L0 weight latency ----
    {
        const int m = t >> 3, n = t & 7;
        const float d0 = __shfl(xv, m * 3 + 0) - __shfl(xv, n * 3 + 0);
        const float d1 = __shfl(xv, m * 3 + 1) - __shfl(xv, n * 3 + 1);
        const float d2 = __shfl(xv, m * 3 + 2) - __shfl(xv, n * 3 + 2);
        out[24 + t] = sqrtf(d0 * d0 + d1 * d1 + d2 * d2);
        out[88 + t] = 0.0f;
    }

    // ---- pipelined layer chain: prefetch layer k+1, compute layer k ----
    ld24(wb, ew1 + r24 * AE_A);
    float h = fmaxf(dot_shfl<AE_A>(wa, xv, b0), 0.f);      // enc0

    ld24(wa, ew2 + r24 * AE_A);
    h = fmaxf(dot_shfl<AE_A>(wb, h, b1), 0.f);             // enc1

    ld24(wb, ew3 + r16 * AE_A);                            // enc3 rows (16x24)
    h = fmaxf(dot_shfl<AE_A>(wa, h, b2), 0.f);             // enc2

    ld16(wa, dw0 + r24 * AE_D);                            // dec0 rows (24x16)
    const float y = dot_shfl<AE_A>(wb, h, b3);             // enc3 -> latent (lanes 0..15)
    if (t < AE_D) out[152 + t] = y;

    ld24(wb, dw1 + r24 * AE_A);
    h = fmaxf(dot_shfl<AE_D>(wa, y, b4), 0.f);             // dec0

    ld24(wa, dw2 + r24 * AE_A);
    h = fmaxf(dot_shfl<AE_A>(wb, h, b5), 0.f);             // dec1

    ld24(wb, dw3 + r24 * AE_A);
    h = fmaxf(dot_shfl<AE_A>(wa, h, b6), 0.f);             // dec2

    h = tanhf(dot_shfl<AE_A>(wb, h, b7));                  // dec3
    if (t < AE_A) out[t] = h;
}

extern "C" void kernel_launch(void* const* d_in, const int* in_sizes, int n_in,
                              void* d_out, int out_size, void* d_ws, size_t ws_size,
                              hipStream_t stream) {
    (void)in_sizes; (void)n_in; (void)d_ws; (void)ws_size; (void)out_size;

    const float* x   = (const float*)d_in[0];
    const float* ew0 = (const float*)d_in[1];
    const float* eb0 = (const float*)d_in[2];
    const float* ew1 = (const float*)d_in[3];
    const float* eb1 = (const float*)d_in[4];
    const float* ew2 = (const float*)d_in[5];
    const float* eb2 = (const float*)d_in[6];
    const float* ew3 = (const float*)d_in[7];
    const float* eb3 = (const float*)d_in[8];
    const float* dw0 = (const float*)d_in[9];
    const float* db0 = (const float*)d_in[10];
    const float* dw1 = (const float*)d_in[11];
    const float* db1 = (const float*)d_in[12];
    const float* dw2 = (const float*)d_in[13];
    const float* db2 = (const float*)d_in[14];
    const float* dw3 = (const float*)d_in[15];
    const float* db3 = (const float*)d_in[16];
    float* out = (float*)d_out;

    ae_fwd_kernel<<<1, 64, 0, stream>>>(
        x, ew0, eb0, ew1, eb1, ew2, eb2, ew3, eb3,
        dw0, db0, dw1, db1, dw2, db2, dw3, db3, out);
}